// Round 2
// baseline (1677.326 us; speedup 1.0000x reference)
//
#include <hip/hip_runtime.h>
#include <hip/hip_bf16.h>

#define TD 2048      // D (model dim)
#define TF 2048      // F (ffn dim)
#define NE 8         // experts
#define NT 4096      // tokens (4*1024)
#define NTOPK 2

typedef __attribute__((ext_vector_type(4))) float f32x4;
typedef __attribute__((ext_vector_type(8))) short bf16x8;
typedef __attribute__((ext_vector_type(4))) short s16x4;

// ---------------- ws layout (bytes) ----------------
// xbf   : ushort [NT][TD]            16 MB   @ 0
// act   : ushort [2*NT][TF]          32 MB   @ 16M
// wgu_t : ushort [NE][2*TF][TD]     128 MB   @ 48M   (rows 0..TF-1 gate, TF..2TF-1 up)
// eo    : float  [2*NT][TD]          64 MB   @ 48M   (ALIAS wgu_t: dead after gemm1)
// wd_t  : ushort [NE][TD][TF]        64 MB   @ 176M
// probs : float  [NT][NE]                    @ 240M
// tok   : int    [NE][NT]
// wt    : float  [NE][NT]
// inv   : int4   [NT]
// cnt   : int    [NE]
// off   : int    [NE]
#define WS_XBF   ((size_t)0)
#define WS_ACT   ((size_t)16 << 20)
#define WS_WGU   ((size_t)48 << 20)
#define WS_EO    ((size_t)48 << 20)
#define WS_WD    ((size_t)176 << 20)
#define WS_PROBS ((size_t)240 << 20)
#define WS_TOK   (WS_PROBS + (size_t)NT * NE * 4)
#define WS_WT    (WS_TOK + (size_t)NE * NT * 4)
#define WS_INV   (WS_WT + (size_t)NE * NT * 4)
#define WS_CNT   (WS_INV + (size_t)NT * 16)
#define WS_OFF   (WS_CNT + 64)

__device__ __forceinline__ unsigned short f2bf(float f) {
  union { float f; unsigned u; } v; v.f = f;
  unsigned r = v.u + 0x7FFFu + ((v.u >> 16) & 1u);   // RNE
  return (unsigned short)(r >> 16);
}

__device__ __forceinline__ void gload_lds16(const void* g, void* l) {
  __builtin_amdgcn_global_load_lds(
      (const __attribute__((address_space(1))) void*)g,
      (__attribute__((address_space(3))) void*)l, 16, 0, 0);
}

// ---------------- x fp32 -> bf16 ----------------
__global__ void k_cvt_x(const float* __restrict__ x, unsigned short* __restrict__ xbf) {
  int i = blockIdx.x * 256 + threadIdx.x;
  float4 v = ((const float4*)x)[i];
  s16x4 r;
  r[0] = (short)f2bf(v.x); r[1] = (short)f2bf(v.y);
  r[2] = (short)f2bf(v.z); r[3] = (short)f2bf(v.w);
  ((s16x4*)xbf)[i] = r;
}

// ---------------- router: 1 wave per token ----------------
__global__ void k_router(const float* __restrict__ x, const float* __restrict__ rw,
                         const float* __restrict__ rb, float* __restrict__ probs,
                         int* __restrict__ tok, float* __restrict__ wt,
                         int4* __restrict__ inv, int* __restrict__ counts) {
  const int t = blockIdx.x;
  const int l = threadIdx.x;
  const float* xr = x + (size_t)t * TD;
  float a0 = 0, a1 = 0, a2 = 0, a3 = 0, a4 = 0, a5 = 0, a6 = 0, a7 = 0;
#pragma unroll 4
  for (int j = 0; j < TD / 64; j++) {
    int d = j * 64 + l;
    float xv = xr[d];
    const float4* wp = (const float4*)(rw + (size_t)d * NE);
    float4 w0 = wp[0], w1 = wp[1];
    a0 += xv * w0.x; a1 += xv * w0.y; a2 += xv * w0.z; a3 += xv * w0.w;
    a4 += xv * w1.x; a5 += xv * w1.y; a6 += xv * w1.z; a7 += xv * w1.w;
  }
#pragma unroll
  for (int off = 32; off > 0; off >>= 1) {
    a0 += __shfl_xor(a0, off); a1 += __shfl_xor(a1, off);
    a2 += __shfl_xor(a2, off); a3 += __shfl_xor(a3, off);
    a4 += __shfl_xor(a4, off); a5 += __shfl_xor(a5, off);
    a6 += __shfl_xor(a6, off); a7 += __shfl_xor(a7, off);
  }
  if (l == 0) {
    float lg[NE] = { a0 + rb[0], a1 + rb[1], a2 + rb[2], a3 + rb[3],
                     a4 + rb[4], a5 + rb[5], a6 + rb[6], a7 + rb[7] };
    float mx = lg[0];
#pragma unroll
    for (int e = 1; e < NE; e++) mx = fmaxf(mx, lg[e]);
    float pe[NE]; float s = 0.f;
#pragma unroll
    for (int e = 0; e < NE; e++) { pe[e] = __expf(lg[e] - mx); s += pe[e]; }
    float inv_s = 1.f / s;
#pragma unroll
    for (int e = 0; e < NE; e++) probs[(size_t)t * NE + e] = pe[e] * inv_s;
    // top-2 (stable: earliest index wins ties, matches lax.top_k)
    int i0 = 0; float b0 = lg[0];
#pragma unroll
    for (int e = 1; e < NE; e++) if (lg[e] > b0) { b0 = lg[e]; i0 = e; }
    int i1 = (i0 == 0) ? 1 : 0; float b1 = lg[i1];
#pragma unroll
    for (int e = 0; e < NE; e++)
      if (e != i0 && lg[e] > b1) { b1 = lg[e]; i1 = e; }
    float e1 = __expf(b1 - b0);
    float rs = 1.f / (1.f + e1);
    float w0v = rs;          // softmax of [b0, b1]
    float w1v = e1 * rs;
    int p0 = atomicAdd(&counts[i0], 1);
    tok[i0 * NT + p0] = t; wt[i0 * NT + p0] = w0v;
    int p1 = atomicAdd(&counts[i1], 1);
    tok[i1 * NT + p1] = t; wt[i1 * NT + p1] = w1v;
    inv[t] = make_int4(i0, p0, i1, p1);
  }
}

// ---------------- finalize: mean_probs, offsets, loads, loss ----------------
__global__ void k_finalize(const float* __restrict__ probs, const int* __restrict__ counts,
                           int* __restrict__ offsets, float* __restrict__ tail) {
  __shared__ float sh[4 * NE];
  int tid = threadIdx.x;
  float s[NE] = {0, 0, 0, 0, 0, 0, 0, 0};
  for (int t = tid; t < NT; t += 256) {
#pragma unroll
    for (int e = 0; e < NE; e++) s[e] += probs[(size_t)t * NE + e];
  }
#pragma unroll
  for (int off = 32; off > 0; off >>= 1) {
#pragma unroll
    for (int e = 0; e < NE; e++) s[e] += __shfl_xor(s[e], off);
  }
  if ((tid & 63) == 0) {
#pragma unroll
    for (int e = 0; e < NE; e++) sh[(tid >> 6) * NE + e] = s[e];
  }
  __syncthreads();
  if (tid == 0) {
    float loss = 0.f; int off = 0;
#pragma unroll
    for (int e = 0; e < NE; e++) {
      float mp = (sh[e] + sh[NE + e] + sh[2 * NE + e] + sh[3 * NE + e]) * (1.f / NT);
      int c = counts[e];
      offsets[e] = off; off += c;
      float df = (float)c / (float)(NT * NTOPK);
      tail[e] = df;
      loss += df * mp;
    }
    tail[NE] = 0.01f * (float)NE * loss;
  }
}

// ---------------- transpose + fp32->bf16 weights ----------------
// tile: 256 src rows (k) x 64 src cols. LDS [256][64] shorts, quad XOR-swizzle.
// REMAP=1: gate/up de-interleave (src col g -> out row (g>>1) + (g&1)*TF)
template <int REMAP>
__global__ __launch_bounds__(256) void k_transpose(
    const float* __restrict__ W, unsigned short* __restrict__ Wt, int R, int C) {
  __shared__ unsigned short lds[256 * 64];
  const int e = blockIdx.z;
  const float* We = W + (size_t)e * R * C;
  unsigned short* Ot = Wt + (size_t)e * R * C;
  const int k0 = blockIdx.y * 256, c0 = blockIdx.x * 64;
  const int tid = threadIdx.x;
  {
    const int rsub = tid >> 4;        // 0..15
    const int cq = tid & 15;          // col-quad
#pragma unroll
    for (int p = 0; p < 16; p++) {
      int row = p * 16 + rsub;
      float4 v = *(const float4*)(We + (size_t)(k0 + row) * C + c0 + cq * 4);
      s16x4 b;
      b[0] = f2bf(v.x); b[1] = f2bf(v.y); b[2] = f2bf(v.z); b[3] = f2bf(v.w);
      *(s16x4*)&lds[row * 64 + ((cq ^ (row & 15)) << 2)] = b;
    }
  }
  __syncthreads();
  {
    const int c = tid & 63, seg = tid >> 6;        // seg uniform per wave
    const int n_src = c0 + c;
    const int orow = REMAP ? ((n_src >> 1) + (n_src & 1) * TF) : n_src;
    unsigned short* dst = Ot + (size_t)orow * R + k0 + seg * 64;
    const int ccq = c >> 2, cr = c & 3;
#pragma unroll
    for (int g = 0; g < 8; g++) {
      bf16x8 val;
#pragma unroll
      for (int ii = 0; ii < 8; ii++) {
        int k = seg * 64 + g * 8 + ii;
        val[ii] = (short)lds[k * 64 + (((ccq ^ (k & 15)) << 2) | cr)];
      }
      *(bf16x8*)(dst + g * 8) = val;
    }
  }
}

// ---------------- GEMM1: act = activation(xbf[tok] @ Wgu + b) ----------------
// tile: 128 rows x 64 act-cols (=128 gu rows of B); 4 waves 2x2, each 64r x 32c(act)
__global__ __launch_bounds__(256) void k_gemm1(
    const unsigned short* __restrict__ xbf, const int* __restrict__ tok,
    const int* __restrict__ counts, const int* __restrict__ offsets,
    const unsigned short* __restrict__ wgu, const float* __restrict__ bgu,
    unsigned short* __restrict__ act) {
  const int e = blockIdx.z;
  const int cnt = counts[e];
  const int m0 = blockIdx.x * 128;         // m fastest: consecutive blocks share B
  if (m0 >= cnt) return;
  const int n0 = blockIdx.y * 64;
  const int offe = offsets[e];
  const unsigned short* Bg = wgu + (size_t)e * (2 * TF) * TD;
  __shared__ unsigned short lA[128 * 32];
  __shared__ unsigned short lB[128 * 32];
  const int tid = threadIdx.x, wid = tid >> 6, lane = tid & 63;
  const int wr = wid >> 1, wc = wid & 1;

  const unsigned short* srcA[2];
  const unsigned short* srcB[2];
#pragma unroll
  for (int j = 0; j < 2; j++) {
    int idx = j * 256 + tid, r = idx >> 2, q = idx & 3;
    int rr = min(m0 + r, cnt - 1);
    srcA[j] = xbf + (size_t)tok[e * NT + rr] * TD + q * 8;
    int srow = (r < 64) ? (n0 + r) : (TF + n0 + (r - 64));
    srcB[j] = Bg + (size_t)srow * TD + q * 8;
  }
  const int cA = lane & 15, q = lane >> 4, kc = q * 8;
  int aoff[4], boff[4];
#pragma unroll
  for (int m = 0; m < 4; m++) aoff[m] = (wr * 64 + m * 16 + cA) * 32 + kc;
#pragma unroll
  for (int n = 0; n < 4; n++) {
    int brow = (n < 2) ? (wc * 32 + n * 16) : (64 + wc * 32 + (n - 2) * 16);
    boff[n] = (brow + cA) * 32 + kc;
  }

  f32x4 acc[4][4] = {};

  for (int kt = 0; kt < TD / 32; kt++) {
    const int k0 = kt * 32;
    __syncthreads();
    gload_lds16(srcA[0] + k0, &lA[(size_t)tid * 8]);
    gload_lds16(srcA[1] + k0, &lA[(size_t)(256 + tid) * 8]);
    gload_lds16(srcB[0] + k0, &lB[(size_t)tid * 8]);
    gload_lds16(srcB[1] + k0, &lB[(size_t)(256 + tid) * 8]);
    __syncthreads();
    bf16x8 af[4];
#pragma unroll
    for (int m = 0; m < 4; m++) af[m] = *(const bf16x8*)&lA[aoff[m]];
#pragma unroll
    for (int n = 0; n < 4; n++) {
      bf16x8 bfr = *(const bf16x8*)&lB[boff[n]];
#pragma unroll
      for (int m = 0; m < 4; m++)
        acc[m][n] = __builtin_amdgcn_mfma_f32_16x16x32_bf16(af[m], bfr, acc[m][n], 0, 0, 0);
    }
  }

  const float* be = bgu + (size_t)e * 2 * TF;
#pragma unroll
  for (int n = 0; n < 2; n++) {
    int col = n0 + wc * 32 + n * 16 + cA;
    float bg = be[2 * col], bu = be[2 * col + 1];
#pragma unroll
    for (int m = 0; m < 4; m++) {
#pragma unroll
      for (int r = 0; r < 4; r++) {
        int row = wr * 64 + m * 16 + q * 4 + r;
        if (m0 + row < cnt) {
          float g = acc[m][n][r] + bg;
          float u = acc[m][n + 2][r] + bu;
          g = fminf(g, 7.0f);
          u = fminf(fmaxf(u, -7.0f), 7.0f);
          float glu = g * (1.0f / (1.0f + __expf(-1.702f * g)));
          float a = (u + 1.0f) * glu;
          act[(size_t)(offe + m0 + row) * TF + col] = f2bf(a);
        }
      }
    }
  }
}

// ---------------- GEMM2: eo[row] = w * (act @ Wd + b_down)  (no atomics) ----
__global__ __launch_bounds__(256) void k_gemm2(
    const unsigned short* __restrict__ act, const float* __restrict__ wt,
    const int* __restrict__ counts, const int* __restrict__ offsets,
    const unsigned short* __restrict__ wd, const float* __restrict__ bd,
    float* __restrict__ eo) {
  const int e = blockIdx.z;
  const int cnt = counts[e];
  const int m0 = blockIdx.x * 128;
  if (m0 >= cnt) return;
  const int d0 = blockIdx.y * 128;
  const int offe = offsets[e];
  const unsigned short* Bd = wd + (size_t)e * TD * TF;
  __shared__ unsigned short lA[128 * 32];
  __shared__ unsigned short lB[128 * 32];
  const int tid = threadIdx.x, wid = tid >> 6, lane = tid & 63;
  const int wr = wid >> 1, wc = wid & 1;

  const unsigned short* srcA[2];
  const unsigned short* srcB[2];
#pragma unroll
  for (int j = 0; j < 2; j++) {
    int idx = j * 256 + tid, r = idx >> 2, q = idx & 3;
    int rr = min(m0 + r, cnt - 1);
    srcA[j] = act + (size_t)(offe + rr) * TF + q * 8;
    srcB[j] = Bd + (size_t)(d0 + r) * TF + q * 8;
  }
  const int cA = lane & 15, q = lane >> 4, kc = q * 8;
  int aoff[4], boff[4];
#pragma unroll
  for (int m = 0; m < 4; m++) aoff[m] = (wr * 64 + m * 16 + cA) * 32 + kc;
#pragma unroll
  for (int n = 0; n < 4; n++) boff[n] = (wc * 64 + n * 16 + cA) * 32 + kc;

  f32x4 acc[4][4] = {};

  for (int kt = 0; kt < TF / 32; kt++) {
    const int k0 = kt * 32;
    __syncthreads();
    gload_lds16(srcA[0] + k0, &lA[(size_t)tid * 8]);
    gload_lds16(srcA[1] + k0, &lA[(size_t)(256 + tid) * 8]);
    gload_lds16(srcB[0] + k0, &lB[(size_t)tid * 8]);
    gload_lds16(srcB[1] + k0, &lB[(size_t)(256 + tid) * 8]);
    __syncthreads();
    bf16x8 af[4];
#pragma unroll
    for (int m = 0; m < 4; m++) af[m] = *(const bf16x8*)&lA[aoff[m]];
#pragma unroll
    for (int n = 0; n < 4; n++) {
      bf16x8 bfr = *(const bf16x8*)&lB[boff[n]];
#pragma unroll
      for (int m = 0; m < 4; m++)
        acc[m][n] = __builtin_amdgcn_mfma_f32_16x16x32_bf16(af[m], bfr, acc[m][n], 0, 0, 0);
    }
  }

  const float* bde = bd + (size_t)e * TD;
#pragma unroll
  for (int n = 0; n < 4; n++) {
    int col = d0 + wc * 64 + n * 16 + cA;
    float bc = bde[col];
#pragma unroll
    for (int m = 0; m < 4; m++) {
#pragma unroll
      for (int r = 0; r < 4; r++) {
        int row = wr * 64 + m * 16 + q * 4 + r;
        int rowe = m0 + row;
        if (rowe < cnt) {
          float w = wt[e * NT + rowe];
          eo[(size_t)(offe + rowe) * TD + col] = w * (acc[m][n][r] + bc);
        }
      }
    }
  }
}

// ---------------- combine: out[t] = eo[slot0] + eo[slot1] ----------------
__global__ void k_combine(const float* __restrict__ eo, const int4* __restrict__ inv,
                          const int* __restrict__ offs, float* __restrict__ out) {
  int i = blockIdx.x * 256 + threadIdx.x;   // float4 index
  int t = i >> 9;                           // TD/4 = 512 float4 per row
  int c = i & 511;
  int4 v = inv[t];
  int s0 = offs[v.x] + v.y, s1 = offs[v.z] + v.w;
  float4 a = ((const float4*)eo)[(size_t)s0 * 512 + c];
  float4 b = ((const float4*)eo)[(size_t)s1 * 512 + c];
  float4 r; r.x = a.x + b.x; r.y = a.y + b.y; r.z = a.z + b.z; r.w = a.w + b.w;
  ((float4*)out)[i] = r;
}

extern "C" void kernel_launch(void* const* d_in, const int* in_sizes, int n_in,
                              void* d_out, int out_size, void* d_ws, size_t ws_size,
                              hipStream_t stream) {
  const float* x   = (const float*)d_in[0];
  const float* rw  = (const float*)d_in[1];
  const float* rb  = (const float*)d_in[2];
  const float* wgu = (const float*)d_in[3];
  const float* bgu = (const float*)d_in[4];
  const float* wdn = (const float*)d_in[5];
  const float* bdn = (const float*)d_in[6];
  float* out = (float*)d_out;
  char* ws = (char*)d_ws;

  unsigned short* xbf  = (unsigned short*)(ws + WS_XBF);
  unsigned short* act  = (unsigned short*)(ws + WS_ACT);
  unsigned short* wgut = (unsigned short*)(ws + WS_WGU);
  unsigned short* wdt  = (unsigned short*)(ws + WS_WD);
  float* eo    = (float*)(ws + WS_EO);
  float* probs = (float*)(ws + WS_PROBS);
  int*   tokl  = (int*)(ws + WS_TOK);
  float* wtl   = (float*)(ws + WS_WT);
  int4*  invm  = (int4*)(ws + WS_INV);
  int*   cnts  = (int*)(ws + WS_CNT);
  int*   offs  = (int*)(ws + WS_OFF);

  hipMemsetAsync(cnts, 0, NE * sizeof(int), stream);

  k_cvt_x<<<(NT * TD) / 1024, 256, 0, stream>>>(x, xbf);
  k_router<<<NT, 64, 0, stream>>>(x, rw, rb, probs, tokl, wtl, invm, cnts);
  k_finalize<<<1, 256, 0, stream>>>(probs, cnts, offs, out + (size_t)NT * TD);
  k_transpose<1><<<dim3(4096 / 64, 2048 / 256, NE), 256, 0, stream>>>(wgu, wgut, TD, 2 * TF);
  k_transpose<0><<<dim3(2048 / 64, 2048 / 256, NE), 256, 0, stream>>>(wdn, wdt, TF, TD);
  k_gemm1<<<dim3(NT / 128, TF / 64, NE), 256, 0, stream>>>(xbf, tokl, cnts, offs, wgut, bgu, act);
  k_gemm2<<<dim3(NT / 128, TD / 128, NE), 256, 0, stream>>>(act, wtl, cnts, offs, wdt, bdn, eo);
  k_combine<<<(NT * TD) / 1024, 256, 0, stream>>>(eo, invm, offs, out);
}